// Round 4
// baseline (1912.828 us; speedup 1.0000x reference)
//
#include <hip/hip_runtime.h>
#include <hip/hip_bf16.h>
#include <stdint.h>

#define TT   4096      // tokens = B*S
#define HD   2048      // hidden
#define ID   1408      // intermediate (routed)
#define NE   16        // experts
#define NK   6         // top-k
#define SHDI 2816      // shared intermediate
#define GRP  64

typedef __hip_bfloat16 bf16;
typedef __attribute__((ext_vector_type(8))) short short8;
typedef __attribute__((ext_vector_type(4))) float floatx4;

__device__ __forceinline__ floatx4 mfma_bf16x(short8 a, short8 b, floatx4 c) {
  return __builtin_amdgcn_mfma_f32_16x16x32_bf16(a, b, c, 0, 0, 0);
}

// async global->LDS, 16B per lane; lds dest = wave-uniform base + lane*16
__device__ __forceinline__ void async16(void* lds, const void* g) {
  __builtin_amdgcn_global_load_lds(
      (const __attribute__((address_space(1))) unsigned int*)g,
      (__attribute__((address_space(3))) unsigned int*)lds, 16, 0, 0);
}

// ---------------- fp32 -> bf16 convert (8 elems/thread) ----------------
__global__ void cvt_bf16_k(const float* __restrict__ in, bf16* __restrict__ o, int n) {
  int i = (blockIdx.x * 256 + threadIdx.x) * 8;
  if (i >= n) return;
  float4 a = *(const float4*)(in + i);
  float4 b = *(const float4*)(in + i + 4);
  __align__(16) bf16 t[8];
  t[0] = __float2bfloat16(a.x); t[1] = __float2bfloat16(a.y);
  t[2] = __float2bfloat16(a.z); t[3] = __float2bfloat16(a.w);
  t[4] = __float2bfloat16(b.x); t[5] = __float2bfloat16(b.y);
  t[6] = __float2bfloat16(b.z); t[7] = __float2bfloat16(b.w);
  *(int4*)(o + i) = *(const int4*)t;
}

// ---------------- gate: logits -> softmax -> top6 -> renorm (pure fp32) ----------------
__global__ void gate_kernel(const float* __restrict__ x, const float* __restrict__ gw,
                            int* __restrict__ topi, float* __restrict__ topw) {
  int t = blockIdx.x;
  int tid = threadIdx.x;
  int e = tid >> 4;      // expert 0..15
  int p = tid & 15;      // partial 0..15
  __shared__ float part[NE][16];
  __shared__ float sc[NE];
  const float* xr = x + (size_t)t * HD;
  const float* gr = gw + (size_t)e * HD;
  float s = 0.f;
  for (int h = p; h < HD; h += 16)
    s += xr[h] * gr[h];
  part[e][p] = s;
  __syncthreads();
  if (tid < NE) {
    float a = 0.f;
    for (int i = 0; i < 16; ++i) a += part[tid][i];
    sc[tid] = a;
  }
  __syncthreads();
  if (tid == 0) {
    float pr[NE];
    float mx = sc[0];
    for (int i = 1; i < NE; ++i) mx = fmaxf(mx, sc[i]);
    float den = 0.f;
    for (int i = 0; i < NE; ++i) { pr[i] = __expf(sc[i] - mx); den += pr[i]; }
    float inv_den = 1.f / den;
    float wsum = 0.f; int ids[NK]; float wv[NK];
    for (int k = 0; k < NK; ++k) {
      int best = 0; float bv = -1.f;
      for (int i = 0; i < NE; ++i) { if (pr[i] > bv) { bv = pr[i]; best = i; } }
      ids[k] = best; wv[k] = bv * inv_den; wsum += bv * inv_den; pr[best] = -2.f;
    }
    float inv = 1.f / (wsum + 1e-20f);
    for (int k = 0; k < NK; ++k) { topi[t*NK + k] = ids[k]; topw[t*NK + k] = wv[k] * inv; }
  }
}

// ---------------- bucket tokens per expert ----------------
__global__ void bucket_kernel(const int* __restrict__ topi, const float* __restrict__ topw,
                              int* __restrict__ counts, int* __restrict__ etok,
                              float* __restrict__ ew) {
  __shared__ int lcnt[NE];
  __shared__ int lbase[NE];
  int tid = threadIdx.x;
  if (tid < NE) lcnt[tid] = 0;
  __syncthreads();
  int t = blockIdx.x * 256 + tid;
  int le[NK], lp[NK]; float lw[NK];
  for (int k = 0; k < NK; ++k) {
    le[k] = topi[t*NK + k];
    lw[k] = topw[t*NK + k];
    lp[k] = atomicAdd(&lcnt[le[k]], 1);
  }
  __syncthreads();
  if (tid < NE) lbase[tid] = atomicAdd(&counts[tid], lcnt[tid]);
  __syncthreads();
  for (int k = 0; k < NK; ++k) {
    int pos = lbase[le[k]] + lp[k];
    etok[le[k]*TT + pos] = t;
    ew[le[k]*TT + pos] = lw[k];
  }
}

__global__ void scan_kernel(const int* __restrict__ counts, int* __restrict__ offs) {
  if (threadIdx.x == 0) {
    int a = 0;
    for (int e = 0; e < NE; ++e) { offs[e] = a; a += counts[e]; }
  }
}

// ---------------- dequant int4-codes (int32) + fp32 scale/zero -> bf16 ----------------
__global__ void dequant_k(const int* __restrict__ q, const float* __restrict__ sc,
                          const float* __restrict__ zp, bf16* __restrict__ o, int indim) {
  int row = blockIdx.x;
  int col = threadIdx.x * 8;
  if (col >= indim) return;
  size_t base = (size_t)row * indim + col;
  size_t sidx = (size_t)row * (indim / GRP) + (col / GRP);
  float z = zp[sidx];
  float s = sc[sidx];
  int4 q0 = *(const int4*)(q + base);
  int4 q1 = *(const int4*)(q + base + 4);
  __align__(16) bf16 t[8];
  t[0] = __float2bfloat16(((float)q0.x - z) * s);
  t[1] = __float2bfloat16(((float)q0.y - z) * s);
  t[2] = __float2bfloat16(((float)q0.z - z) * s);
  t[3] = __float2bfloat16(((float)q0.w - z) * s);
  t[4] = __float2bfloat16(((float)q1.x - z) * s);
  t[5] = __float2bfloat16(((float)q1.y - z) * s);
  t[6] = __float2bfloat16(((float)q1.z - z) * s);
  t[7] = __float2bfloat16(((float)q1.w - z) * s);
  *(int4*)(o + base) = *(const int4*)t;
}

// ---------------- fused gate+up grouped GEMM + SwiGLU ----------------
// C[m,n] tiles 128x128, BK=64; LDS layout [kchunk(8)][row(128)][8 bf16]
__global__ __launch_bounds__(256, 2)
void gateup_gemm(const short* __restrict__ X,
                 const short* __restrict__ Bg_all, const short* __restrict__ Bu_all,
                 size_t b_estride, int e0, int nrows,
                 const int* __restrict__ etok, const int* __restrict__ counts,
                 const int* __restrict__ offs,
                 bf16* __restrict__ Y, int N) {
  int ez = blockIdx.z, mt = blockIdx.y, nt = blockIdx.x;
  int e = e0 + ez;
  int cnt = counts ? counts[e] : nrows;
  int m0 = mt * 128;
  if (m0 >= cnt) return;
  int yoff = offs ? (offs[e] - offs[e0]) : 0;   // chunk-local row base
  const short* Bg = Bg_all + (size_t)ez * b_estride;
  const short* Bu = Bu_all + (size_t)ez * b_estride;
  const int* tok = etok ? etok + e * TT : nullptr;

  __shared__ __align__(16) short sA[8192], sG[8192], sU[8192];
  int tid = threadIdx.x, wave = tid >> 6, lane = tid & 63, quad = lane >> 4, r = lane & 15;
  int wm = wave & 1, wn = wave >> 1;

  const short *ap[4], *gp[4], *up[4];
  int kcj[4], ldso[4];
#pragma unroll
  for (int jj = 0; jj < 4; ++jj) {
    int j = wave * 4 + jj;
    kcj[jj] = j >> 1;
    int rg = (j & 1) * 64;
    ldso[jj] = (kcj[jj] * 128 + rg) * 8;
    int row = m0 + rg + lane;
    int trow = tok ? tok[row < cnt ? row : cnt - 1] : row;
    ap[jj] = X + (size_t)trow * HD;
    int n = nt * 128 + rg + lane;
    gp[jj] = Bg + (size_t)n * HD;
    up[jj] = Bu + (size_t)n * HD;
  }

  floatx4 accg[4][4], accu[4][4];
#pragma unroll
  for (int mi = 0; mi < 4; ++mi)
#pragma unroll
    for (int ni = 0; ni < 4; ++ni) { accg[mi][ni] = (floatx4)0.f; accu[mi][ni] = (floatx4)0.f; }

  for (int k0 = 0; k0 < HD; k0 += 64) {
#pragma unroll
    for (int jj = 0; jj < 4; ++jj) {
      int go = k0 + kcj[jj] * 8;
      async16(sA + ldso[jj], ap[jj] + go);
      async16(sG + ldso[jj], gp[jj] + go);
      async16(sU + ldso[jj], up[jj] + go);
    }
    __syncthreads();
    const short8* Av = (const short8*)sA;
    const short8* Gv = (const short8*)sG;
    const short8* Uv = (const short8*)sU;
#pragma unroll
    for (int ks = 0; ks < 2; ++ks) {
      int kq = (ks * 4 + quad) * 128;
      short8 af[4], bfr[4];
#pragma unroll
      for (int mi = 0; mi < 4; ++mi) af[mi] = Av[kq + wm * 64 + mi * 16 + r];
#pragma unroll
      for (int ni = 0; ni < 4; ++ni) bfr[ni] = Gv[kq + wn * 64 + ni * 16 + r];
#pragma unroll
      for (int mi = 0; mi < 4; ++mi)
#pragma unroll
        for (int ni = 0; ni < 4; ++ni)
          accg[mi][ni] = mfma_bf16x(af[mi], bfr[ni], accg[mi][ni]);
#pragma unroll
      for (int ni = 0; ni < 4; ++ni) bfr[ni] = Uv[kq + wn * 64 + ni * 16 + r];
#pragma unroll
      for (int mi = 0; mi < 4; ++mi)
#pragma unroll
        for (int ni = 0; ni < 4; ++ni)
          accu[mi][ni] = mfma_bf16x(af[mi], bfr[ni], accu[mi][ni]);
    }
    __syncthreads();
  }

#pragma unroll
  for (int mi = 0; mi < 4; ++mi)
#pragma unroll
    for (int rg2 = 0; rg2 < 4; ++rg2) {
      int slot = m0 + wm * 64 + mi * 16 + quad * 4 + rg2;
      if (slot < cnt) {
        bf16* yr = Y + (size_t)(yoff + slot) * N + nt * 128 + wn * 64 + r;
#pragma unroll
        for (int ni = 0; ni < 4; ++ni) {
          float g = accg[mi][ni][rg2], u = accu[mi][ni][rg2];
          yr[ni * 16] = __float2bfloat16(g * u / (1.f + __expf(-g)));
        }
      }
    }
}

// ---------------- down GEMM; MODE 0: weighted atomic scatter; MODE 1: +accum -> fp32 out ----------------
template <int MODE>
__global__ __launch_bounds__(256, 2)
void down_gemm(const short* __restrict__ Abase, const short* __restrict__ Ball,
               size_t b_estride, int kdim, int e0, int nrows,
               const int* __restrict__ counts, const int* __restrict__ offs,
               const int* __restrict__ etok, const float* __restrict__ ew,
               float* __restrict__ accum, float* __restrict__ outp) {
  int ez = blockIdx.z, mt = blockIdx.y, nt = blockIdx.x;
  int e = e0 + ez;
  int cnt = counts ? counts[e] : nrows;
  int m0 = mt * 128;
  if (m0 >= cnt) return;
  const short* A = Abase + (offs ? (size_t)(offs[e] - offs[e0]) * kdim : 0);
  const short* B = Ball + (size_t)ez * b_estride;

  __shared__ __align__(16) short sA[8192], sB[8192];
  int tid = threadIdx.x, wave = tid >> 6, lane = tid & 63, quad = lane >> 4, r = lane & 15;
  int wm = wave & 1, wn = wave >> 1;

  const short *ap[4], *bp[4];
  int kcj[4], ldso[4];
#pragma unroll
  for (int jj = 0; jj < 4; ++jj) {
    int j = wave * 4 + jj;
    kcj[jj] = j >> 1;
    int rg = (j & 1) * 64;
    ldso[jj] = (kcj[jj] * 128 + rg) * 8;
    ap[jj] = A + (size_t)(m0 + rg + lane) * kdim;
    bp[jj] = B + (size_t)(nt * 128 + rg + lane) * kdim;
  }

  floatx4 acc[4][4];
#pragma unroll
  for (int mi = 0; mi < 4; ++mi)
#pragma unroll
    for (int ni = 0; ni < 4; ++ni) acc[mi][ni] = (floatx4)0.f;

  for (int k0 = 0; k0 < kdim; k0 += 64) {
#pragma unroll
    for (int jj = 0; jj < 4; ++jj) {
      int go = k0 + kcj[jj] * 8;
      async16(sA + ldso[jj], ap[jj] + go);
      async16(sB + ldso[jj], bp[jj] + go);
    }
    __syncthreads();
    const short8* Av = (const short8*)sA;
    const short8* Bv = (const short8*)sB;
#pragma unroll
    for (int ks = 0; ks < 2; ++ks) {
      int kq = (ks * 4 + quad) * 128;
      short8 af[4], bfr[4];
#pragma unroll
      for (int mi = 0; mi < 4; ++mi) af[mi] = Av[kq + wm * 64 + mi * 16 + r];
#pragma unroll
      for (int ni = 0; ni < 4; ++ni) bfr[ni] = Bv[kq + wn * 64 + ni * 16 + r];
#pragma unroll
      for (int mi = 0; mi < 4; ++mi)
#pragma unroll
        for (int ni = 0; ni < 4; ++ni)
          acc[mi][ni] = mfma_bf16x(af[mi], bfr[ni], acc[mi][ni]);
    }
    __syncthreads();
  }

#pragma unroll
  for (int mi = 0; mi < 4; ++mi)
#pragma unroll
    for (int rg2 = 0; rg2 < 4; ++rg2) {
      int slot = m0 + wm * 64 + mi * 16 + quad * 4 + rg2;
      if (slot < cnt) {
        int col0 = nt * 128 + wn * 64 + r;
        if (MODE == 0) {
          int tk = etok[e * TT + slot];
          float w = ew[e * TT + slot];
          float* arow = accum + (size_t)tk * HD + col0;
#pragma unroll
          for (int ni = 0; ni < 4; ++ni)
            atomicAdd(arow + ni * 16, acc[mi][ni][rg2] * w);
        } else {
          const float* arow = accum + (size_t)slot * HD + col0;
          float* orow = outp + (size_t)slot * HD + col0;
#pragma unroll
          for (int ni = 0; ni < 4; ++ni)
            orow[ni * 16] = acc[mi][ni][rg2] + arow[ni * 16];
        }
      }
    }
}

// ---------------- launch ----------------
extern "C" void kernel_launch(void* const* d_in, const int* in_sizes, int n_in,
                              void* d_out, int out_size, void* d_ws, size_t ws_size,
                              hipStream_t stream) {
  const float* x      = (const float*)d_in[0];
  const float* gate_w = (const float*)d_in[1];
  const int*   wq_g   = (const int*)  d_in[2];
  const float* sc_g   = (const float*)d_in[3];
  const float* zp_g   = (const float*)d_in[4];
  const int*   wq_u   = (const int*)  d_in[5];
  const float* sc_u   = (const float*)d_in[6];
  const float* zp_u   = (const float*)d_in[7];
  const int*   wq_d   = (const int*)  d_in[8];
  const float* sc_d   = (const float*)d_in[9];
  const float* zp_d   = (const float*)d_in[10];
  const float* wg_sh  = (const float*)d_in[11];
  const float* wu_sh  = (const float*)d_in[12];
  const float* wd_sh  = (const float*)d_in[13];
  float* out = (float*)d_out;

  // ---- adaptive workspace tiering: pick largest experts-per-chunk that fits ----
  auto pad = [](size_t b) { return (b + 255) & ~(size_t)255; };
  size_t fixedBytes = pad((size_t)TT * HD * 2)          // xb
                    + 3 * pad((size_t)SHDI * HD * 2)    // shared weights bf16
                    + pad((size_t)TT * HD * 4)          // accum
                    + 2 * pad((size_t)TT * NK * 4)      // topi/topw
                    + 2 * pad((size_t)NE * TT * 4)      // etok/ew
                    + 2 * pad(256) + 256;               // counts/offs + slack
  int ECH = 1;
  for (int c = 16; c >= 1; c >>= 1) {
    size_t slot = pad((size_t)c * ID * HD * 2);
    size_t ybufB = pad(((size_t)c * TT + 128) * ID * 2);
    if (2 * slot + ybufB + fixedBytes <= ws_size) { ECH = c; break; }
  }

  char* p = (char*)d_ws;
  auto alloc = [&](size_t bytes) { char* q = p; p += (bytes + 255) & ~(size_t)255; return q; };
  bf16*  slotA = (bf16*)alloc((size_t)ECH * ID * HD * 2);         // deq gate -> deq down
  bf16*  slotB = (bf16*)alloc((size_t)ECH * ID * HD * 2);         // deq up
  size_t ybufBytes = ((size_t)ECH * TT + 128) * ID * 2;
  bf16*  ybuf  = (bf16*)alloc(ybufBytes);                          // SwiGLU out; reused for shared
  bf16*  xb    = (bf16*)alloc((size_t)TT * HD * 2);                // x in bf16
  bf16*  wgsb  = (bf16*)alloc((size_t)SHDI * HD * 2);
  bf16*  wusb  = (bf16*)alloc((size_t)SHDI * HD * 2);
  bf16*  wdsb  = (bf16*)alloc((size_t)HD * SHDI * 2);
  float* accum = (float*)alloc((size_t)TT * HD * 4);
  int*   topi  = (int*)  alloc((size_t)TT * NK * 4);
  float* topw  = (float*)alloc((size_t)TT * NK * 4);
  int*   etok  = (int*)  alloc((size_t)NE * TT * 4);
  float* ew    = (float*)alloc((size_t)NE * TT * 4);
  int*   counts= (int*)  alloc(256);
  int*   offs  = (int*)  alloc(256);

  hipMemsetAsync(counts, 0, 64, stream);
  hipMemsetAsync(accum, 0, (size_t)TT * HD * 4, stream);

  // fp32 -> bf16 conversions
  cvt_bf16_k<<<(TT * HD / 8 + 255) / 256, 256, 0, stream>>>(x, xb, TT * HD);
  cvt_bf16_k<<<(SHDI * HD / 8 + 255) / 256, 256, 0, stream>>>(wg_sh, wgsb, SHDI * HD);
  cvt_bf16_k<<<(SHDI * HD / 8 + 255) / 256, 256, 0, stream>>>(wu_sh, wusb, SHDI * HD);
  cvt_bf16_k<<<(HD * SHDI / 8 + 255) / 256, 256, 0, stream>>>(wd_sh, wdsb, HD * SHDI);

  gate_kernel<<<TT, 256, 0, stream>>>(x, gate_w, topi, topw);
  bucket_kernel<<<TT / 256, 256, 0, stream>>>(topi, topw, counts, etok, ew);
  scan_kernel<<<1, 64, 0, stream>>>(counts, offs);

  // routed experts, ECH at a time
  for (int e0 = 0; e0 < NE; e0 += ECH) {
    size_t wqo = (size_t)e0 * ID * HD;
    size_t sco = (size_t)e0 * ID * (HD / GRP);
    dequant_k<<<ECH * ID, 256, 0, stream>>>(wq_g + wqo, sc_g + sco, zp_g + sco, slotA, HD);
    dequant_k<<<ECH * ID, 256, 0, stream>>>(wq_u + wqo, sc_u + sco, zp_u + sco, slotB, HD);
    gateup_gemm<<<dim3(ID / 128, TT / 128, ECH), 256, 0, stream>>>(
        (const short*)xb, (const short*)slotA, (const short*)slotB,
        (size_t)ID * HD, e0, TT, etok, counts, offs, ybuf, ID);
    size_t sdo = (size_t)e0 * HD * (ID / GRP);
    dequant_k<<<ECH * HD, 256, 0, stream>>>(wq_d + wqo, sc_d + sdo, zp_d + sdo, slotA, ID);
    down_gemm<0><<<dim3(HD / 128, TT / 128, ECH), 256, 0, stream>>>(
        (const short*)ybuf, (const short*)slotA, (size_t)HD * ID, ID, e0, TT,
        counts, offs, etok, ew, accum, nullptr);
  }

  // shared expert through ybuf, in token chunks sized to fit
  int TC = TT;
  while ((size_t)TC * SHDI * 2 > ybufBytes) TC >>= 1;   // ECH>=2 -> 4096; ECH=1 -> 2048
  for (int t0 = 0; t0 < TT; t0 += TC) {
    gateup_gemm<<<dim3(SHDI / 128, TC / 128, 1), 256, 0, stream>>>(
        (const short*)(xb + (size_t)t0 * HD), (const short*)wgsb, (const short*)wusb,
        0, 0, TC, nullptr, nullptr, nullptr, ybuf, SHDI);
    down_gemm<1><<<dim3(HD / 128, TC / 128, 1), 256, 0, stream>>>(
        (const short*)ybuf, (const short*)wdsb, 0, SHDI, 0, TC,
        nullptr, nullptr, nullptr, nullptr, accum + (size_t)t0 * HD,
        out + (size_t)t0 * HD);
  }
}